// Round 4
// baseline (3566.712 us; speedup 1.0000x reference)
//
#include <hip/hip_runtime.h>
#include <hip/hip_bf16.h>
#include <cstdint>

#define S_LEN   4608
#define HID     2048
#define VOCAB_N 32768
#define CAPV    30.0f
#define IGNORE_IDX (-100)
#define NT512   512      // vocab partial tiles of 64 columns
#define XBLK    4608     // cvt blocks covering X (9437184 el / 2048 per block)

typedef short bf16x8 __attribute__((ext_vector_type(8)));
typedef float f32x4  __attribute__((ext_vector_type(4)));
typedef int   i32x4v __attribute__((ext_vector_type(4)));
typedef int   i32x8  __attribute__((ext_vector_type(8)));

// ---------- helpers ----------
__device__ __forceinline__ unsigned short f2bf_rtne(float f) {
    unsigned int u = __float_as_uint(f);
    unsigned int r = u + 0x7fffu + ((u >> 16) & 1u);
    return (unsigned short)(r >> 16);
}
__device__ __forceinline__ float bfr(float f) {  // fp32 -> bf16 -> fp32 (RTNE)
    unsigned int u = __float_as_uint(f);
    unsigned int r = u + 0x7fffu + ((u >> 16) & 1u);
    return __uint_as_float(r & 0xffff0000u);
}
__device__ __forceinline__ float bf2f(unsigned int us) { return __uint_as_float(us << 16); }
__device__ __forceinline__ float bf_lo(unsigned int u) { return __uint_as_float(u << 16); }
__device__ __forceinline__ float bf_hi(unsigned int u) { return __uint_as_float(u & 0xffff0000u); }
__device__ __forceinline__ float bfdot2(unsigned int x, unsigned int w) {
    return bf_lo(x) * bf_lo(w) + bf_hi(x) * bf_hi(w);
}
// Reference-matched softcap: logit, logit/CAP and tanh rounded through bf16.
__device__ __forceinline__ float softcap_ref(float logit) {
    float lb = bfr(logit);
    float x  = bfr(lb / CAPV);
    float e  = __expf(2.0f * x);
    float t  = bfr((e - 1.0f) / (e + 1.0f));
    return CAPV * t;
}
// fp32 -> OCP e4m3fn byte (RTNE, saturate to 448). Input pre-scaled.
__device__ __forceinline__ unsigned int f2e4m3(float x) {
    unsigned int u = __float_as_uint(x);
    unsigned int s = (u >> 24) & 0x80u;
    unsigned int a = u & 0x7fffffffu;
    unsigned int m;
    if (a >= 0x43e00000u) {                 // >= 448: saturate
        m = 0x7eu;
    } else if (a < 0x3c800000u) {           // < 2^-6: subnormal, units of 2^-9
        m = (unsigned int)__float2int_rn(__uint_as_float(a) * 512.0f);
    } else {                                // normal: round mantissa to 3 bits
        unsigned int r = a + 0x7ffffu + ((a >> 20) & 1u);
        m = (r >> 20) - 960u;
    }
    return s | m;
}

// ---------- kernel 0: convert X (fp32->bf16 + fp8*32) and W (bf16->fp8*256) ----------
__global__ void cvt_kernel(const float* __restrict__ h,
                           const unsigned short* __restrict__ W,
                           unsigned short* __restrict__ Xb,
                           unsigned char* __restrict__ Xf8,
                           unsigned char* __restrict__ Wf8,
                           float* __restrict__ out) {
    const int bid = blockIdx.x;
    const int t   = threadIdx.x;
    if (bid == 0 && t == 0) out[0] = 0.0f;   // zero accumulator (runs before row_reduce)
    if (bid < XBLK) {
        const size_t i = ((size_t)bid * 256 + t) * 8;
        float4 v0 = *(const float4*)(h + i);
        float4 v1 = *(const float4*)(h + i + 4);
        unsigned short b[8];
        b[0] = f2bf_rtne(v0.x); b[1] = f2bf_rtne(v0.y);
        b[2] = f2bf_rtne(v0.z); b[3] = f2bf_rtne(v0.w);
        b[4] = f2bf_rtne(v1.x); b[5] = f2bf_rtne(v1.y);
        b[6] = f2bf_rtne(v1.z); b[7] = f2bf_rtne(v1.w);
        ushort4 o0 = {b[0], b[1], b[2], b[3]};
        ushort4 o1 = {b[4], b[5], b[6], b[7]};
        *(ushort4*)(Xb + i)     = o0;
        *(ushort4*)(Xb + i + 4) = o1;
        // fp8 from the bf16-rounded value (matches ref's bf16 cast), scaled by 2^5
        unsigned int p0 = 0, p1 = 0;
        #pragma unroll
        for (int j = 0; j < 4; ++j) p0 |= f2e4m3(bf2f(b[j])     * 32.0f) << (8 * j);
        #pragma unroll
        for (int j = 0; j < 4; ++j) p1 |= f2e4m3(bf2f(b[4 + j]) * 32.0f) << (8 * j);
        uint2 p = {p0, p1};
        *(uint2*)(Xf8 + i) = p;
    } else {
        const size_t i = ((size_t)(bid - XBLK) * 256 + t) * 8;
        uint4 w = *(const uint4*)(W + i);    // 8 bf16
        unsigned int p0 = 0, p1 = 0;
        p0 |= f2e4m3(bf_lo(w.x) * 256.0f);
        p0 |= f2e4m3(bf_hi(w.x) * 256.0f) << 8;
        p0 |= f2e4m3(bf_lo(w.y) * 256.0f) << 16;
        p0 |= f2e4m3(bf_hi(w.y) * 256.0f) << 24;
        p1 |= f2e4m3(bf_lo(w.z) * 256.0f);
        p1 |= f2e4m3(bf_hi(w.z) * 256.0f) << 8;
        p1 |= f2e4m3(bf_lo(w.w) * 256.0f) << 16;
        p1 |= f2e4m3(bf_hi(w.w) * 256.0f) << 24;
        uint2 p = {p0, p1};
        *(uint2*)(Wf8 + i) = p;
    }
}

// ---------- kernel 1: MX-fp8 GEMM + softcap + per-row partial sum-exp ----------
// BK=128 bytes (one 16x16x128 K-step per iter), 128B LDS rows = full bank width.
// XOR swizzle: LDS slot s of row r holds global 16B chunk s ^ (r&7) -> conflict-free.
// Scales all 1.0 (0x7F); real scaling (X*2^5, W*2^8) baked into quant, descale 2^-13.
// __launch_bounds__(256,3): cap VGPR ~170, 3 blocks/CU (m97 sweet spot), no spill.
__global__ __launch_bounds__(256, 3)
void gemm_lse_kernel(const unsigned char* __restrict__ Xf8,
                     const unsigned char* __restrict__ Wf8,
                     float* __restrict__ partL) {
    __shared__ __align__(16) unsigned char As[128 * 128];   // 16 KB
    __shared__ __align__(16) unsigned char Bs[128 * 128];   // 16 KB

    const int tid  = threadIdx.x;
    const int wave = tid >> 6;
    const int lane = tid & 63;
    const int tileM = blockIdx.y * 128;
    const int tileN = blockIdx.x * 128;

    // staging: 8 rows x 8 slots per wave-issue; lane -> row lane>>3, slot lane&7
    const int rr = lane >> 3;
    const int sl = lane & 7;
    const int cg = sl ^ rr;                  // global chunk fetched into slot sl of row rr

    const unsigned char* Abase = Xf8 + (size_t)(tileM + wave * 32) * HID + cg * 16;
    const unsigned char* Bbase = Wf8 + (size_t)(tileN + wave * 32) * HID + cg * 16;

    const int wr = wave >> 1, wc = wave & 1; // 2x2 wave layout, 64x64 each
    const int q  = lane >> 4, l16 = lane & 15;

    // fragment reads: lane needs global chunks q and q+4 of its row -> swizzled slots
    const int sA0 = ((q)     ^ (l16 & 7)) * 16;
    const int sA1 = ((q + 4) ^ (l16 & 7)) * 16;
    int arow[4], brow[4];
    #pragma unroll
    for (int t = 0; t < 4; ++t) {
        arow[t] = (wr * 64 + t * 16 + l16) * 128;
        brow[t] = (wc * 64 + t * 16 + l16) * 128;
    }

    f32x4 acc[4][4] = {};

    for (int k0 = 0; k0 < HID; k0 += 128) {
        __syncthreads();
        #pragma unroll
        for (int j = 0; j < 4; ++j) {
            const unsigned char* ga = Abase + (size_t)(j * 8 + rr) * HID + k0;
            __builtin_amdgcn_global_load_lds(
                (const __attribute__((address_space(1))) void*)ga,
                (__attribute__((address_space(3))) void*)&As[(wave * 32 + j * 8) * 128],
                16, 0, 0);
            const unsigned char* gb = Bbase + (size_t)(j * 8 + rr) * HID + k0;
            __builtin_amdgcn_global_load_lds(
                (const __attribute__((address_space(1))) void*)gb,
                (__attribute__((address_space(3))) void*)&Bs[(wave * 32 + j * 8) * 128],
                16, 0, 0);
        }
        __syncthreads();

        i32x8 av[4], bv[4];
        #pragma unroll
        for (int t = 0; t < 4; ++t) {
            i32x4v lo = *(const i32x4v*)&As[arow[t] + sA0];
            i32x4v hi = *(const i32x4v*)&As[arow[t] + sA1];
            av[t] = __builtin_shufflevector(lo, hi, 0, 1, 2, 3, 4, 5, 6, 7);
        }
        #pragma unroll
        for (int t = 0; t < 4; ++t) {
            i32x4v lo = *(const i32x4v*)&Bs[brow[t] + sA0];
            i32x4v hi = *(const i32x4v*)&Bs[brow[t] + sA1];
            bv[t] = __builtin_shufflevector(lo, hi, 0, 1, 2, 3, 4, 5, 6, 7);
        }
        #pragma unroll
        for (int tj = 0; tj < 4; ++tj)
            #pragma unroll
            for (int ti = 0; ti < 4; ++ti)
                acc[ti][tj] = __builtin_amdgcn_mfma_scale_f32_16x16x128_f8f6f4(
                    av[ti], bv[tj], acc[ti][tj],
                    0, 0,                  // cbsz=fp8(e4m3), blgp=fp8(e4m3)
                    0, 0x7f7f7f7f,         // opsel_a, scale_a = 1.0
                    0, 0x7f7f7f7f);        // opsel_b, scale_b = 1.0
    }

    // Epilogue: C layout col = lane&15 (vocab), row = q*4 + reg (seq). Descale 2^-13.
    // Outer loop NOT unrolled: keeps one ti-slice of transcendental temps live.
    const int rowbase = tileM + wr * 64;
    const int ntile   = blockIdx.x * 2 + wc;
    #pragma unroll 1
    for (int ti = 0; ti < 4; ++ti) {
        #pragma unroll
        for (int r = 0; r < 4; ++r) {
            float s = 0.0f;
            #pragma unroll
            for (int tj = 0; tj < 4; ++tj)
                s += __expf(softcap_ref(acc[ti][tj][r] * (1.0f / 8192.0f)));
            s += __shfl_xor(s, 1);
            s += __shfl_xor(s, 2);
            s += __shfl_xor(s, 4);
            s += __shfl_xor(s, 8);
            if (l16 == 0)
                partL[(size_t)(rowbase + ti * 16 + q * 4 + r) * NT512 + ntile] = s;
        }
    }
}

// ---------- kernel 2: per-row label logit (exact bf16 path) + logsumexp -> atomic ----------
__global__ void row_reduce_kernel(const unsigned short* __restrict__ X,
                                  const unsigned short* __restrict__ W,
                                  const int* __restrict__ ids,
                                  const int* __restrict__ am,
                                  const float* __restrict__ partL,
                                  float* __restrict__ out) {
    __shared__ float blk[4];
    const int wave = threadIdx.x >> 6;
    const int lane = threadIdx.x & 63;
    const int r = blockIdx.x * 4 + wave;

    int lab = IGNORE_IDX;
    if (r < S_LEN - 1 && am[r + 1] != 0) lab = ids[r + 1];
    const bool valid = (lab >= 0 && lab < VOCAB_N);

    float dot = 0.0f;
    if (valid) {
        const unsigned short* xr = X + (size_t)r   * HID;
        const unsigned short* wr = W + (size_t)lab * HID;
        #pragma unroll
        for (int c = 0; c < 4; ++c) {
            const int off = c * 512 + lane * 8;
            uint4 xu = *(const uint4*)(xr + off);
            uint4 wu = *(const uint4*)(wr + off);
            dot += bfdot2(xu.x, wu.x) + bfdot2(xu.y, wu.y) +
                   bfdot2(xu.z, wu.z) + bfdot2(xu.w, wu.w);
        }
    }
    #pragma unroll
    for (int m = 1; m < 64; m <<= 1) dot += __shfl_xor(dot, m);

    float L = 0.0f;
    const float* pr = partL + (size_t)r * NT512;
    #pragma unroll
    for (int i = 0; i < 8; ++i) L += pr[i * 64 + lane];
    #pragma unroll
    for (int m = 1; m < 64; m <<= 1) L += __shfl_xor(L, m);

    if (lane == 0) {
        float loss = 0.0f;
        if (valid) loss = logf(L) - softcap_ref(dot);
        blk[wave] = loss;
    }
    __syncthreads();
    if (threadIdx.x == 0)
        atomicAdd(out, blk[0] + blk[1] + blk[2] + blk[3]);
}

extern "C" void kernel_launch(void* const* d_in, const int* in_sizes, int n_in,
                              void* d_out, int out_size, void* d_ws, size_t ws_size,
                              hipStream_t stream) {
    const unsigned short* W  = (const unsigned short*)d_in[0];  // bf16 [V, H]
    const float*  hidden     = (const float*)d_in[1];           // fp32 [1, S, H]
    const int*    ids        = (const int*)d_in[2];             // [1, S]
    const int*    am         = (const int*)d_in[3];             // [1, S]
    float* out = (float*)d_out;

    char* ws = (char*)d_ws;
    unsigned short* Xb  = (unsigned short*)ws;                               // 18.9 MB
    float* partL        = (float*)(ws + (size_t)S_LEN * HID * 2);            //  9.4 MB
    unsigned char* Xf8  = (unsigned char*)(ws + (size_t)S_LEN * HID * 2
                                              + (size_t)S_LEN * NT512 * 4);  //  9.4 MB
    unsigned char* Wf8  = Xf8 + (size_t)S_LEN * HID;                         // 64.0 MB

    // X blocks + W blocks in one dispatch
    cvt_kernel<<<XBLK + (VOCAB_N * HID / 2048), 256, 0, stream>>>(
        hidden, W, Xb, Xf8, Wf8, out);

    dim3 g(VOCAB_N / 128, S_LEN / 128);
    gemm_lse_kernel<<<g, 256, 0, stream>>>(Xf8, Wf8, partL);

    row_reduce_kernel<<<S_LEN / 4, 256, 0, stream>>>(Xb, W, ids, am, partL, out);
}

// Round 5
// 2218.214 us; speedup vs baseline: 1.6079x; 1.6079x over previous
//
#include <hip/hip_runtime.h>
#include <hip/hip_bf16.h>
#include <cstdint>

#define S_LEN   4608
#define HID     2048
#define VOCAB_N 32768
#define CAPV    30.0f
#define IGNORE_IDX (-100)
#define NT512   512      // vocab partial tiles of 64 columns
#define XBLK    4608     // cvt blocks covering X (9437184 el / 2048 per block)

typedef short bf16x8 __attribute__((ext_vector_type(8)));
typedef float f32x4  __attribute__((ext_vector_type(4)));
typedef int   i32x4v __attribute__((ext_vector_type(4)));
typedef int   i32x8  __attribute__((ext_vector_type(8)));

// ---------- helpers ----------
__device__ __forceinline__ unsigned short f2bf_rtne(float f) {
    unsigned int u = __float_as_uint(f);
    unsigned int r = u + 0x7fffu + ((u >> 16) & 1u);
    return (unsigned short)(r >> 16);
}
__device__ __forceinline__ float bfr(float f) {  // fp32 -> bf16 -> fp32 (RTNE)
    unsigned int u = __float_as_uint(f);
    unsigned int r = u + 0x7fffu + ((u >> 16) & 1u);
    return __uint_as_float(r & 0xffff0000u);
}
__device__ __forceinline__ float bf2f(unsigned int us) { return __uint_as_float(us << 16); }
__device__ __forceinline__ float bf_lo(unsigned int u) { return __uint_as_float(u << 16); }
__device__ __forceinline__ float bf_hi(unsigned int u) { return __uint_as_float(u & 0xffff0000u); }
__device__ __forceinline__ float bfdot2(unsigned int x, unsigned int w) {
    return bf_lo(x) * bf_lo(w) + bf_hi(x) * bf_hi(w);
}
// Reference-matched softcap: logit, logit/CAP and tanh rounded through bf16.
__device__ __forceinline__ float softcap_ref(float logit) {
    float lb = bfr(logit);
    float x  = bfr(lb / CAPV);
    float e  = __expf(2.0f * x);
    float t  = bfr((e - 1.0f) / (e + 1.0f));
    return CAPV * t;
}
// fp32 -> OCP e4m3fn byte (RTNE, saturate to 448). Input pre-scaled.
__device__ __forceinline__ unsigned int f2e4m3(float x) {
    unsigned int u = __float_as_uint(x);
    unsigned int s = (u >> 24) & 0x80u;
    unsigned int a = u & 0x7fffffffu;
    unsigned int m;
    if (a >= 0x43e00000u) {                 // >= 448: saturate
        m = 0x7eu;
    } else if (a < 0x3c800000u) {           // < 2^-6: subnormal, units of 2^-9
        m = (unsigned int)__float2int_rn(__uint_as_float(a) * 512.0f);
    } else {                                // normal: round mantissa to 3 bits
        unsigned int r = a + 0x7ffffu + ((a >> 20) & 1u);
        m = (r >> 20) - 960u;
    }
    return s | m;
}

// ---------- kernel 0: convert X (fp32->bf16 + fp8*32) and W (bf16->fp8*256) ----------
__global__ void cvt_kernel(const float* __restrict__ h,
                           const unsigned short* __restrict__ W,
                           unsigned short* __restrict__ Xb,
                           unsigned char* __restrict__ Xf8,
                           unsigned char* __restrict__ Wf8,
                           float* __restrict__ out) {
    const int bid = blockIdx.x;
    const int t   = threadIdx.x;
    if (bid == 0 && t == 0) out[0] = 0.0f;   // zero accumulator (runs before row_reduce)
    if (bid < XBLK) {
        const size_t i = ((size_t)bid * 256 + t) * 8;
        float4 v0 = *(const float4*)(h + i);
        float4 v1 = *(const float4*)(h + i + 4);
        unsigned short b[8];
        b[0] = f2bf_rtne(v0.x); b[1] = f2bf_rtne(v0.y);
        b[2] = f2bf_rtne(v0.z); b[3] = f2bf_rtne(v0.w);
        b[4] = f2bf_rtne(v1.x); b[5] = f2bf_rtne(v1.y);
        b[6] = f2bf_rtne(v1.z); b[7] = f2bf_rtne(v1.w);
        ushort4 o0 = {b[0], b[1], b[2], b[3]};
        ushort4 o1 = {b[4], b[5], b[6], b[7]};
        *(ushort4*)(Xb + i)     = o0;
        *(ushort4*)(Xb + i + 4) = o1;
        // fp8 from the bf16-rounded value (matches ref's bf16 cast), scaled by 2^5
        unsigned int p0 = 0, p1 = 0;
        #pragma unroll
        for (int j = 0; j < 4; ++j) p0 |= f2e4m3(bf2f(b[j])     * 32.0f) << (8 * j);
        #pragma unroll
        for (int j = 0; j < 4; ++j) p1 |= f2e4m3(bf2f(b[4 + j]) * 32.0f) << (8 * j);
        uint2 p = {p0, p1};
        *(uint2*)(Xf8 + i) = p;
    } else {
        const size_t i = ((size_t)(bid - XBLK) * 256 + t) * 8;
        uint4 w = *(const uint4*)(W + i);    // 8 bf16
        unsigned int p0 = 0, p1 = 0;
        p0 |= f2e4m3(bf_lo(w.x) * 256.0f);
        p0 |= f2e4m3(bf_hi(w.x) * 256.0f) << 8;
        p0 |= f2e4m3(bf_lo(w.y) * 256.0f) << 16;
        p0 |= f2e4m3(bf_hi(w.y) * 256.0f) << 24;
        p1 |= f2e4m3(bf_lo(w.z) * 256.0f);
        p1 |= f2e4m3(bf_hi(w.z) * 256.0f) << 8;
        p1 |= f2e4m3(bf_lo(w.w) * 256.0f) << 16;
        p1 |= f2e4m3(bf_hi(w.w) * 256.0f) << 24;
        uint2 p = {p0, p1};
        *(uint2*)(Wf8 + i) = p;
    }
}

// ---------- kernel 1: MX-fp8 GEMM + softcap + per-row partial sum-exp ----------
// BK=128 bytes, XOR-swizzled LDS (slot = chunk ^ (row&7)) -> conflict-free b128.
// Scales all 1.0 (0x7F); real scaling (X*2^5, W*2^8) baked into quant, descale 2^-13.
// Register discipline (R4 lesson): bv streamed one fragment at a time (live set
// ~= acc 64 + av 32 + bv 8 + addr ~25), epilogue fully unrolled (acc must never
// be runtime-indexed), bound (256,2) = 256-reg budget -> no spill, 2 blocks/CU.
__global__ __launch_bounds__(256, 2)
void gemm_lse_kernel(const unsigned char* __restrict__ Xf8,
                     const unsigned char* __restrict__ Wf8,
                     float* __restrict__ partL) {
    __shared__ __align__(16) unsigned char As[128 * 128];   // 16 KB
    __shared__ __align__(16) unsigned char Bs[128 * 128];   // 16 KB

    const int tid  = threadIdx.x;
    const int wave = tid >> 6;
    const int lane = tid & 63;
    const int tileM = blockIdx.y * 128;
    const int tileN = blockIdx.x * 128;

    // staging: 8 rows x 8 slots per wave-issue; lane -> row lane>>3, slot lane&7
    const int rr = lane >> 3;
    const int sl = lane & 7;
    const int cg = sl ^ rr;                  // global chunk fetched into slot sl of row rr

    const unsigned char* Abase = Xf8 + (size_t)(tileM + wave * 32) * HID + cg * 16;
    const unsigned char* Bbase = Wf8 + (size_t)(tileN + wave * 32) * HID + cg * 16;

    const int wr = wave >> 1, wc = wave & 1; // 2x2 wave layout, 64x64 each
    const int q  = lane >> 4, l16 = lane & 15;

    // fragment reads: lane needs global chunks q and q+4 of its row -> swizzled slots
    const int sA0 = ((q)     ^ (l16 & 7)) * 16;
    const int sA1 = ((q + 4) ^ (l16 & 7)) * 16;
    int arow[4], brow[4];
    #pragma unroll
    for (int t = 0; t < 4; ++t) {
        arow[t] = (wr * 64 + t * 16 + l16) * 128;
        brow[t] = (wc * 64 + t * 16 + l16) * 128;
    }

    f32x4 acc[4][4] = {};

    for (int k0 = 0; k0 < HID; k0 += 128) {
        __syncthreads();
        #pragma unroll
        for (int j = 0; j < 4; ++j) {
            const unsigned char* ga = Abase + (size_t)(j * 8 + rr) * HID + k0;
            __builtin_amdgcn_global_load_lds(
                (const __attribute__((address_space(1))) void*)ga,
                (__attribute__((address_space(3))) void*)&As[(wave * 32 + j * 8) * 128],
                16, 0, 0);
            const unsigned char* gb = Bbase + (size_t)(j * 8 + rr) * HID + k0;
            __builtin_amdgcn_global_load_lds(
                (const __attribute__((address_space(1))) void*)gb,
                (__attribute__((address_space(3))) void*)&Bs[(wave * 32 + j * 8) * 128],
                16, 0, 0);
        }
        __syncthreads();

        i32x8 av[4];
        #pragma unroll
        for (int t = 0; t < 4; ++t) {
            i32x4v lo = *(const i32x4v*)&As[arow[t] + sA0];
            i32x4v hi = *(const i32x4v*)&As[arow[t] + sA1];
            av[t] = __builtin_shufflevector(lo, hi, 0, 1, 2, 3, 4, 5, 6, 7);
        }
        #pragma unroll
        for (int tj = 0; tj < 4; ++tj) {
            i32x4v lo = *(const i32x4v*)&Bs[brow[tj] + sA0];
            i32x4v hi = *(const i32x4v*)&Bs[brow[tj] + sA1];
            i32x8 bv = __builtin_shufflevector(lo, hi, 0, 1, 2, 3, 4, 5, 6, 7);
            #pragma unroll
            for (int ti = 0; ti < 4; ++ti)
                acc[ti][tj] = __builtin_amdgcn_mfma_scale_f32_16x16x128_f8f6f4(
                    av[ti], bv, acc[ti][tj],
                    0, 0,                  // cbsz=fp8(e4m3), blgp=fp8(e4m3)
                    0, 0x7f7f7f7f,         // opsel_a, scale_a = 1.0
                    0, 0x7f7f7f7f);        // opsel_b, scale_b = 1.0
        }
    }

    // Epilogue: C layout col = lane&15 (vocab), row = q*4 + reg (seq). Descale 2^-13.
    // Fully unrolled: acc indices must stay compile-time constants (no scratch).
    const int rowbase = tileM + wr * 64;
    const int ntile   = blockIdx.x * 2 + wc;
    #pragma unroll
    for (int ti = 0; ti < 4; ++ti) {
        #pragma unroll
        for (int r = 0; r < 4; ++r) {
            float s = 0.0f;
            #pragma unroll
            for (int tj = 0; tj < 4; ++tj)
                s += __expf(softcap_ref(acc[ti][tj][r] * (1.0f / 8192.0f)));
            s += __shfl_xor(s, 1);
            s += __shfl_xor(s, 2);
            s += __shfl_xor(s, 4);
            s += __shfl_xor(s, 8);
            if (l16 == 0)
                partL[(size_t)(rowbase + ti * 16 + q * 4 + r) * NT512 + ntile] = s;
        }
    }
}

// ---------- kernel 2: per-row label logit (exact bf16 path) + logsumexp -> atomic ----------
__global__ void row_reduce_kernel(const unsigned short* __restrict__ X,
                                  const unsigned short* __restrict__ W,
                                  const int* __restrict__ ids,
                                  const int* __restrict__ am,
                                  const float* __restrict__ partL,
                                  float* __restrict__ out) {
    __shared__ float blk[4];
    const int wave = threadIdx.x >> 6;
    const int lane = threadIdx.x & 63;
    const int r = blockIdx.x * 4 + wave;

    int lab = IGNORE_IDX;
    if (r < S_LEN - 1 && am[r + 1] != 0) lab = ids[r + 1];
    const bool valid = (lab >= 0 && lab < VOCAB_N);

    float dot = 0.0f;
    if (valid) {
        const unsigned short* xr = X + (size_t)r   * HID;
        const unsigned short* wr = W + (size_t)lab * HID;
        #pragma unroll
        for (int c = 0; c < 4; ++c) {
            const int off = c * 512 + lane * 8;
            uint4 xu = *(const uint4*)(xr + off);
            uint4 wu = *(const uint4*)(wr + off);
            dot += bfdot2(xu.x, wu.x) + bfdot2(xu.y, wu.y) +
                   bfdot2(xu.z, wu.z) + bfdot2(xu.w, wu.w);
        }
    }
    #pragma unroll
    for (int m = 1; m < 64; m <<= 1) dot += __shfl_xor(dot, m);

    float L = 0.0f;
    const float* pr = partL + (size_t)r * NT512;
    #pragma unroll
    for (int i = 0; i < 8; ++i) L += pr[i * 64 + lane];
    #pragma unroll
    for (int m = 1; m < 64; m <<= 1) L += __shfl_xor(L, m);

    if (lane == 0) {
        float loss = 0.0f;
        if (valid) loss = logf(L) - softcap_ref(dot);
        blk[wave] = loss;
    }
    __syncthreads();
    if (threadIdx.x == 0)
        atomicAdd(out, blk[0] + blk[1] + blk[2] + blk[3]);
}

extern "C" void kernel_launch(void* const* d_in, const int* in_sizes, int n_in,
                              void* d_out, int out_size, void* d_ws, size_t ws_size,
                              hipStream_t stream) {
    const unsigned short* W  = (const unsigned short*)d_in[0];  // bf16 [V, H]
    const float*  hidden     = (const float*)d_in[1];           // fp32 [1, S, H]
    const int*    ids        = (const int*)d_in[2];             // [1, S]
    const int*    am         = (const int*)d_in[3];             // [1, S]
    float* out = (float*)d_out;

    char* ws = (char*)d_ws;
    unsigned short* Xb  = (unsigned short*)ws;                               // 18.9 MB
    float* partL        = (float*)(ws + (size_t)S_LEN * HID * 2);            //  9.4 MB
    unsigned char* Xf8  = (unsigned char*)(ws + (size_t)S_LEN * HID * 2
                                              + (size_t)S_LEN * NT512 * 4);  //  9.4 MB
    unsigned char* Wf8  = Xf8 + (size_t)S_LEN * HID;                         // 64.0 MB

    // X blocks + W blocks in one dispatch
    cvt_kernel<<<XBLK + (VOCAB_N * HID / 2048), 256, 0, stream>>>(
        hidden, W, Xb, Xf8, Wf8, out);

    dim3 g(VOCAB_N / 128, S_LEN / 128);
    gemm_lse_kernel<<<g, 256, 0, stream>>>(Xf8, Wf8, partL);

    row_reduce_kernel<<<S_LEN / 4, 256, 0, stream>>>(Xb, W, ids, am, partL, out);
}

// Round 6
// 1031.685 us; speedup vs baseline: 3.4572x; 2.1501x over previous
//
#include <hip/hip_runtime.h>
#include <hip/hip_bf16.h>
#include <cstdint>

#define S_LEN   4608
#define HID     2048
#define VOCAB_N 32768
#define CAPV    30.0f
#define IGNORE_IDX (-100)
#define NT512   512   // vocab partial tiles of 64 columns

typedef short bf16x8 __attribute__((ext_vector_type(8)));
typedef float f32x4  __attribute__((ext_vector_type(4)));

// ---------- helpers ----------
__device__ __forceinline__ unsigned short f2bf_rtne(float f) {
    unsigned int u = __float_as_uint(f);
    unsigned int r = u + 0x7fffu + ((u >> 16) & 1u);
    return (unsigned short)(r >> 16);
}
__device__ __forceinline__ float bfr(float f) {  // fp32 -> bf16 -> fp32 (RTNE)
    unsigned int u = __float_as_uint(f);
    unsigned int r = u + 0x7fffu + ((u >> 16) & 1u);
    return __uint_as_float(r & 0xffff0000u);
}
__device__ __forceinline__ float bf_lo(unsigned int u) { return __uint_as_float(u << 16); }
__device__ __forceinline__ float bf_hi(unsigned int u) { return __uint_as_float(u & 0xffff0000u); }
__device__ __forceinline__ float bfdot2(unsigned int x, unsigned int w) {
    return bf_lo(x) * bf_lo(w) + bf_hi(x) * bf_hi(w);
}
// Reference-matched softcap: logit, logit/CAP and tanh rounded through bf16.
__device__ __forceinline__ float softcap_ref(float logit) {
    float lb = bfr(logit);
    float x  = bfr(lb / CAPV);
    float e  = __expf(2.0f * x);
    float t  = bfr((e - 1.0f) / (e + 1.0f));
    return CAPV * t;
}

// ---------- kernel 0: fp32 -> bf16 convert of hidden (+ zero the output scalar) ----------
__global__ void cvt_kernel(const float* __restrict__ h, unsigned short* __restrict__ xb,
                           float* __restrict__ out) {
    if (blockIdx.x == 0 && threadIdx.x == 0) out[0] = 0.0f;
    int i = blockIdx.x * blockDim.x + threadIdx.x;   // one float4 per thread, exact cover
    float4 v = ((const float4*)h)[i];
    ushort4 o;
    o.x = f2bf_rtne(v.x); o.y = f2bf_rtne(v.y);
    o.z = f2bf_rtne(v.z); o.w = f2bf_rtne(v.w);
    ((ushort4*)xb)[i] = o;
}

// ---------- kernel 1: fused bf16 GEMM + softcap + per-row partial sum-exp ----------
// R1 structure (BK=32, 16 KB LDS, no launch_bounds -> VGPR ~72, ~3 blocks/CU) plus:
//  * XOR swizzle: LDS 16B-slot s of row r holds global chunk s ^ ((r>>2)&3).
//    Fragment reads then hit 2 lanes per 4-bank group = conflict-free (m136).
//  * N-major grid: blockIdx.x = M-tile (36), blockIdx.y = N-tile (256) so the
//    ~768 co-resident blocks reuse W tiles from L2/L3 (FETCH ~= W once).
__global__ void gemm_lse_kernel(const unsigned short* __restrict__ X,
                                const unsigned short* __restrict__ W,
                                float* __restrict__ partL) {
    __shared__ __align__(16) unsigned short As[128 * 32];
    __shared__ __align__(16) unsigned short Bs[128 * 32];

    const int tid  = threadIdx.x;
    const int wave = tid >> 6;
    const int lane = tid & 63;
    const int tileM = blockIdx.x * 128;
    const int tileN = blockIdx.y * 128;

    // staging lane map: row = lane>>2 (16 rows/issue), slot = lane&3 (16B chunks).
    // slot s of row r receives GLOBAL chunk s ^ ((r>>2)&3).
    const int lr = lane >> 2;
    const int cg = (lane & 3) ^ ((lane >> 4) & 3);   // (lane>>4)&3 == (lr>>2)&3

    const unsigned short* Abase = X + (size_t)(tileM + wave * 32) * HID + cg * 8;
    const unsigned short* Bbase = W + (size_t)(tileN + wave * 32) * HID + cg * 8;

    const int wr  = wave >> 1, wc = wave & 1;     // 2x2 wave layout, 64x64 each
    const int q   = lane >> 4, l16 = lane & 15;

    // fragment read: global chunk q of row (.. + t*16 + l16) lives at slot q ^ (l16>>2)
    const int swz = (q ^ (l16 >> 2)) * 8;         // element offset within 32-el row
    int arow[4], brow[4];
    #pragma unroll
    for (int t = 0; t < 4; ++t) {
        arow[t] = (wr * 64 + t * 16 + l16) * 32 + swz;
        brow[t] = (wc * 64 + t * 16 + l16) * 32 + swz;
    }

    f32x4 acc[4][4] = {};

    for (int k0 = 0; k0 < HID; k0 += 32) {
        __syncthreads();   // protect LDS from previous iteration's readers
        #pragma unroll
        for (int j = 0; j < 2; ++j) {
            const unsigned short* ga = Abase + (size_t)(j * 16 + lr) * HID + k0;
            __builtin_amdgcn_global_load_lds(
                (const __attribute__((address_space(1))) void*)ga,
                (__attribute__((address_space(3))) void*)&As[(wave * 32 + j * 16) * 32],
                16, 0, 0);
            const unsigned short* gb = Bbase + (size_t)(j * 16 + lr) * HID + k0;
            __builtin_amdgcn_global_load_lds(
                (const __attribute__((address_space(1))) void*)gb,
                (__attribute__((address_space(3))) void*)&Bs[(wave * 32 + j * 16) * 32],
                16, 0, 0);
        }
        __syncthreads();   // drains vmcnt for the LDS-direct loads

        bf16x8 av[4], bv[4];
        #pragma unroll
        for (int t = 0; t < 4; ++t) {
            av[t] = *(const bf16x8*)&As[arow[t]];
            bv[t] = *(const bf16x8*)&Bs[brow[t]];
        }
        #pragma unroll
        for (int ti = 0; ti < 4; ++ti)
            #pragma unroll
            for (int tj = 0; tj < 4; ++tj)
                acc[ti][tj] = __builtin_amdgcn_mfma_f32_16x16x32_bf16(
                    av[ti], bv[tj], acc[ti][tj], 0, 0, 0);
    }

    // Epilogue: C layout col = lane&15 (vocab), row = q*4 + reg (seq).
    const int rowbase = tileM + wr * 64;
    const int ntile   = blockIdx.y * 2 + wc;
    #pragma unroll
    for (int ti = 0; ti < 4; ++ti) {
        #pragma unroll
        for (int r = 0; r < 4; ++r) {
            float s = 0.0f;
            #pragma unroll
            for (int tj = 0; tj < 4; ++tj)
                s += __expf(softcap_ref(acc[ti][tj][r]));
            s += __shfl_xor(s, 1);
            s += __shfl_xor(s, 2);
            s += __shfl_xor(s, 4);
            s += __shfl_xor(s, 8);
            if (l16 == 0)
                partL[(size_t)(rowbase + ti * 16 + q * 4 + r) * NT512 + ntile] = s;
        }
    }
}

// ---------- kernel 2: per-row label logit + logsumexp reduce -> atomic total ----------
__global__ void row_reduce_kernel(const unsigned short* __restrict__ X,
                                  const unsigned short* __restrict__ W,
                                  const int* __restrict__ ids,
                                  const int* __restrict__ am,
                                  const float* __restrict__ partL,
                                  float* __restrict__ out) {
    __shared__ float blk[4];
    const int wave = threadIdx.x >> 6;
    const int lane = threadIdx.x & 63;
    const int r = blockIdx.x * 4 + wave;

    int lab = IGNORE_IDX;
    if (r < S_LEN - 1 && am[r + 1] != 0) lab = ids[r + 1];
    const bool valid = (lab >= 0 && lab < VOCAB_N);

    float dot = 0.0f;
    if (valid) {
        const unsigned short* xr = X + (size_t)r   * HID;
        const unsigned short* wr = W + (size_t)lab * HID;
        #pragma unroll
        for (int c = 0; c < 4; ++c) {
            const int off = c * 512 + lane * 8;
            uint4 xu = *(const uint4*)(xr + off);
            uint4 wu = *(const uint4*)(wr + off);
            dot += bfdot2(xu.x, wu.x) + bfdot2(xu.y, wu.y) +
                   bfdot2(xu.z, wu.z) + bfdot2(xu.w, wu.w);
        }
    }
    #pragma unroll
    for (int m = 1; m < 64; m <<= 1) dot += __shfl_xor(dot, m);

    float L = 0.0f;
    const float* pr = partL + (size_t)r * NT512;
    #pragma unroll
    for (int i = 0; i < 8; ++i) L += pr[i * 64 + lane];
    #pragma unroll
    for (int m = 1; m < 64; m <<= 1) L += __shfl_xor(L, m);

    if (lane == 0) {
        float loss = 0.0f;
        if (valid) loss = logf(L) - softcap_ref(dot);
        blk[wave] = loss;
    }
    __syncthreads();
    if (threadIdx.x == 0)
        atomicAdd(out, blk[0] + blk[1] + blk[2] + blk[3]);
}

extern "C" void kernel_launch(void* const* d_in, const int* in_sizes, int n_in,
                              void* d_out, int out_size, void* d_ws, size_t ws_size,
                              hipStream_t stream) {
    const unsigned short* W  = (const unsigned short*)d_in[0];  // bf16 [V, H]
    const float*  hidden     = (const float*)d_in[1];           // fp32 [1, S, H]
    const int*    ids        = (const int*)d_in[2];             // [1, S]
    const int*    am         = (const int*)d_in[3];             // [1, S]
    float* out = (float*)d_out;

    char* ws = (char*)d_ws;
    unsigned short* Xb = (unsigned short*)ws;                          // S*H bf16
    float* partL       = (float*)(ws + (size_t)S_LEN * HID * 2);       // S*512 f32

    cvt_kernel<<<(S_LEN * HID / 4) / 256, 256, 0, stream>>>(hidden, Xb, out);

    dim3 g(S_LEN / 128, VOCAB_N / 128);    // x = M (36), y = N (256): W reuse across x
    gemm_lse_kernel<<<g, 256, 0, stream>>>(Xb, W, partL);

    row_reduce_kernel<<<S_LEN / 4, 256, 0, stream>>>(Xb, W, ids, am, partL, out);
}